// Round 1
// baseline (455.356 us; speedup 1.0000x reference)
//
#include <hip/hip_runtime.h>
#include <hip/hip_cooperative_groups.h>

namespace cg = cooperative_groups;

// ---------------------------------------------------------------------------
// Threefry2x32 (JAX-compatible), usable at compile time (constexpr) and runtime
// PRNG layer assumes jax_threefry_partitionable=True (JAX >= 0.4.30 default):
//   fold_in(key,d)        = threefry(key,(0,d))            (both modes)
//   split(key,n)[m]       = threefry(key,(0,m))  full pair (foldlike)
//   random_bits(32)[i]    = v0 ^ v1 of threefry(key,(0,i)) (counter mode)
// ---------------------------------------------------------------------------
struct KP { unsigned a, b; };

__host__ __device__ constexpr unsigned rotl32(unsigned x, int d) {
  return (x << d) | (x >> (32 - d));
}

__host__ __device__ constexpr KP tf2x32(unsigned k0, unsigned k1, unsigned x0, unsigned x1) {
  unsigned k2 = k0 ^ k1 ^ 0x1BD11BDAu;
  unsigned v0 = x0 + k0;
  unsigned v1 = x1 + k1;
  const int R[5][4] = {{13,15,26,6},{17,29,16,24},{13,15,26,6},{17,29,16,24},{13,15,26,6}};
  const unsigned KI[5][2] = {{k1, k2 + 1u},{k2, k0 + 2u},{k0, k1 + 3u},{k1, k2 + 4u},{k2, k0 + 5u}};
  for (int g = 0; g < 5; ++g) {
    for (int r = 0; r < 4; ++r) {
      v0 += v1;
      v1 = rotl32(v1, R[g][r]);
      v1 ^= v0;
    }
    v0 += KI[g][0];
    v1 += KI[g][1];
  }
  return KP{v0, v1};
}

// Compile-time key schedule: root key (0,42); per-level fold_in + foldlike
// split(5); corner key fold_in(1000).
struct AllKeys {
  unsigned lk[9][5][2];   // [level][stream: centers,top,left,right,bottom][k0,k1]
  unsigned ck[2];         // corner key
};

__host__ __device__ constexpr AllKeys make_keys() {
  AllKeys K{};
  for (int l = 0; l < 9; ++l) {
    KP base = tf2x32(0u, 42u, 0u, (unsigned)l);          // fold_in(key, level)
    for (int m = 0; m < 5; ++m) {                        // foldlike split
      KP s = tf2x32(base.a, base.b, 0u, (unsigned)m);
      K.lk[l][m][0] = s.a;
      K.lk[l][m][1] = s.b;
    }
  }
  KP ck = tf2x32(0u, 42u, 0u, 1000u);                    // fold_in(key, 1000)
  K.ck[0] = ck.a;
  K.ck[1] = ck.b;
  return K;
}

constexpr AllKeys KEYS = make_keys();

#define NG 513

// partitionable random_bits(32): element i = v0 ^ v1 of cipher(key, (0, i))
__device__ inline unsigned rbits(unsigned k0, unsigned k1, unsigned i) {
  KP o = tf2x32(k0, k1, 0u, i);
  return o.a ^ o.b;
}

__device__ inline float bits_to_u(unsigned b, float r) {
  float u = __uint_as_float((b >> 9) | 0x3f800000u) - 1.0f;   // [0,1)
  return fmaxf(-r, u * (2.0f * r) - r);                       // uniform(-r, r)
}

__device__ inline float draw_u(const unsigned* kk, unsigned i, float r) {
  return bits_to_u(rbits(kk[0], kk[1], i), r);
}

// recompute center of cell (a,b) at given level (reads only coarser-level hm)
__device__ inline float cell_center(const float* hm, int level, int g, int L,
                                    int a, int b, float r) {
  int lo_i = a * L, hi_i = lo_i + L, lo_j = b * L, hi_j = lo_j + L;
  float nw = hm[lo_i * NG + lo_j], ne = hm[lo_i * NG + hi_j];
  float sw = hm[hi_i * NG + lo_j], se = hm[hi_i * NG + hi_j];
  return (nw + ne + sw + se) * 0.25f +
         draw_u(KEYS.lk[level][0], (unsigned)(a * g + b), r);
}

__device__ inline void do_cell(float* hm, int level, int i, int j) {
  int g = 1 << level;
  int L = 512 >> level;
  int h = L >> 1;
  float r = 1.0f / (float)(level + 1);
  int lo_i = i * L, hi_i = lo_i + L, mi_i = lo_i + h;
  int lo_j = j * L, hi_j = lo_j + L, mi_j = lo_j + h;
  float nw = hm[lo_i * NG + lo_j], ne = hm[lo_i * NG + hi_j];
  float sw = hm[hi_i * NG + lo_j], se = hm[hi_i * NG + hi_j];
  unsigned m = (unsigned)(i * g + j);

  float c = (nw + ne + sw + se) * 0.25f + draw_u(KEYS.lk[level][0], m, r);
  hm[mi_i * NG + mi_j] = c;

  // right edge midpoint (temp_r: own center, wraps to column 0 on last column)
  float tr = (j < g - 1) ? c : cell_center(hm, level, g, L, i, 0, r);
  float right = (c + ne + se + tr) * 0.25f + draw_u(KEYS.lk[level][3], m, r);
  hm[mi_i * NG + hi_j] = right;

  // bottom edge midpoint (temp_b: own center, wraps to row 0 on last row)
  float tb = (i < g - 1) ? c : cell_center(hm, level, g, L, 0, j, r);
  float bottom = (c + sw + se + tb) * 0.25f + draw_u(KEYS.lk[level][4], m, r);
  hm[hi_i * NG + mi_j] = bottom;

  if (i == 0) {  // top row midpoints
    float cg1 = (g == 1) ? c : cell_center(hm, level, g, L, g - 1, j, r);
    float top = (c + hm[lo_j] + hm[hi_j] + cg1) * 0.25f +
                draw_u(KEYS.lk[level][1], (unsigned)j, r);
    hm[mi_j] = top;
  }
  if (j == 0) {  // left column midpoints
    float cg1 = (g == 1) ? c : cell_center(hm, level, g, L, i, g - 1, r);
    float left = (c + hm[lo_i * NG] + hm[hi_i * NG] + cg1) * 0.25f +
                 draw_u(KEYS.lk[level][2], (unsigned)i, r);
    hm[mi_i * NG] = left;
  }
}

__device__ inline unsigned enc_f(float f) {
  unsigned u = __float_as_uint(f);
  return (u & 0x80000000u) ? ~u : (u | 0x80000000u);
}
__device__ inline float dec_f(unsigned e) {
  unsigned u = (e & 0x80000000u) ? (e & 0x7FFFFFFFu) : ~e;
  return __uint_as_float(u);
}

// ---------------------------------------------------------------------------
// Single cooperative kernel: corners + levels 0..8 + global minmax.
// 256 blocks x 256 threads (1 block/CU guaranteed co-resident).
// 4 grid.sync()s replace 5 kernel boundaries of the old chain.
// ---------------------------------------------------------------------------
__global__ void __launch_bounds__(256) k_ds_coop(float* hm, unsigned* mmx) {
  cg::grid_group grid = cg::this_grid();
  const int tid = threadIdx.x;
  const int gtid = blockIdx.x * 256 + tid;

  if (blockIdx.x == 0) {
    if (tid == 0) {
#pragma unroll
      for (int q = 0; q < 4; ++q) {
        float v = bits_to_u(rbits(KEYS.ck[0], KEYS.ck[1], (unsigned)q), 1.0f);
        int y = (q >> 1) ? 512 : 0;
        int x = (q & 1) ? 512 : 0;
        hm[y * NG + x] = v;
      }
      mmx[0] = 0xFFFFFFFFu;  // min slot (atomicMin target)
      mmx[1] = 0u;           // max slot (atomicMax target)
    }
    __syncthreads();
    // levels 0..5: at most 1024 cells, 256 threads loop over cells
    for (int lvl = 0; lvl <= 5; ++lvl) {
      int g = 1 << lvl;
      for (int c = tid; c < g * g; c += 256)
        do_cell(hm, lvl, c >> lvl, c & (g - 1));
      __syncthreads();
    }
  }
  __threadfence();
  grid.sync();
  if (gtid < 4096) do_cell(hm, 6, gtid >> 6, gtid & 63);
  __threadfence();
  grid.sync();
  if (gtid < 16384) do_cell(hm, 7, gtid >> 7, gtid & 127);
  __threadfence();
  grid.sync();
  do_cell(hm, 8, gtid >> 8, gtid & 255);
  __threadfence();
  grid.sync();

  // global min/max over the finished 513x513 grid (L2-resident)
  float mn = 3.4e38f, mx = -3.4e38f;
  for (int idx = gtid; idx < NG * NG; idx += 256 * 256) {
    float v = hm[idx];
    mn = fminf(mn, v);
    mx = fmaxf(mx, v);
  }
#pragma unroll
  for (int off = 32; off >= 1; off >>= 1) {
    mn = fminf(mn, __shfl_down(mn, off, 64));
    mx = fmaxf(mx, __shfl_down(mx, off, 64));
  }
  if ((tid & 63) == 0) {
    atomicMin(&mmx[0], enc_f(mn));
    atomicMax(&mmx[1], enc_f(mx));
  }
}

// ---------------------------------------------------------------------------
// Fallback path (non-cooperative), in case cooperative capture is refused.
// ---------------------------------------------------------------------------
__global__ void k_ds_small(float* hm, unsigned* mmx) {
  int tid = threadIdx.x;
  if (tid == 0) {
#pragma unroll
    for (int q = 0; q < 4; ++q) {
      float v = bits_to_u(rbits(KEYS.ck[0], KEYS.ck[1], (unsigned)q), 1.0f);
      int y = (q >> 1) ? 512 : 0;
      int x = (q & 1) ? 512 : 0;
      hm[y * NG + x] = v;
    }
    mmx[0] = 0xFFFFFFFFu;
    mmx[1] = 0u;
  }
  __syncthreads();
  for (int lvl = 0; lvl <= 5; ++lvl) {
    int g = 1 << lvl;
    if (tid < g * g) do_cell(hm, lvl, tid >> lvl, tid & (g - 1));
    __syncthreads();
  }
}

__global__ void k_level(float* hm, int level) {
  int g = 1 << level;
  int gt = blockIdx.x * blockDim.x + threadIdx.x;
  do_cell(hm, level, gt >> level, gt & (g - 1));
}

__global__ void k_minmax(const float* hm, unsigned* mmx) {
  int gtid = blockIdx.x * blockDim.x + threadIdx.x;
  int nthreads = gridDim.x * blockDim.x;
  float mn = 3.4e38f, mx = -3.4e38f;
  for (int idx = gtid; idx < NG * NG; idx += nthreads) {
    float v = hm[idx];
    mn = fminf(mn, v);
    mx = fmaxf(mx, v);
  }
#pragma unroll
  for (int off = 32; off >= 1; off >>= 1) {
    mn = fminf(mn, __shfl_down(mn, off, 64));
    mx = fmaxf(mx, __shfl_down(mx, off, 64));
  }
  if ((threadIdx.x & 63) == 0) {
    atomicMin(&mmx[0], enc_f(mn));
    atomicMax(&mmx[1], enc_f(mx));
  }
}

// ---------------------------------------------------------------------------
// Fused noise + apply: each thread owns ONE float4 pixel position, computes
// the bilinear-resized normalized noise once, and streams it across 24 of
// the 96 planes (4 thread-groups cover all planes). rn never hits memory.
// out = clip(img*(1-rn) + rn, 0, 1)
// ---------------------------------------------------------------------------
__global__ void __launch_bounds__(1024) k_apply_fused(
    const float4* __restrict__ img, const float* __restrict__ hm,
    const unsigned* __restrict__ mmx, float4* __restrict__ out) {
  int t = blockIdx.x * 1024 + threadIdx.x;   // 0..262143
  int pos4 = t & 65535;                      // within-plane float4 index
  int pg = t >> 16;                          // plane group 0..3 (24 planes each)
  int oy = pos4 >> 7;                        // 128 float4 per row
  int ox = (pos4 & 127) << 2;

  // exact two-tap triangle weights: kernel_scale = 513/512
  const float csc = 512.0f / 513.0f;
  float dy = (float)(2 * oy + 1) * (1.0f / 1024.0f);
  float wy0 = 1.0f - dy * csc;
  float wy1 = 1.0f - (1.0f - dy) * csc;
  float sy = wy0 + wy1;
  wy0 /= sy; wy1 /= sy;

  const float* r0 = hm + oy * NG + ox;
  const float* r1 = r0 + NG;
  float a0 = r0[0], a1 = r0[1], a2 = r0[2], a3 = r0[3], a4 = r0[4];
  float b0 = r1[0], b1 = r1[1], b2 = r1[2], b3 = r1[3], b4 = r1[4];

  float mn = dec_f(mmx[0]), mx = dec_f(mmx[1]);

  float4 n;
  {
    float dx = (float)(2 * ox + 1) * (1.0f / 1024.0f);
    float wx0 = 1.0f - dx * csc, wx1 = 1.0f - (1.0f - dx) * csc;
    float sx = wx0 + wx1; wx0 /= sx; wx1 /= sx;
    float v = wy0 * (wx0 * a0 + wx1 * a1) + wy1 * (wx0 * b0 + wx1 * b1);
    n.x = 0.5f * ((v - mn) / (mx - mn));
  }
  {
    float dx = (float)(2 * (ox + 1) + 1) * (1.0f / 1024.0f);
    float wx0 = 1.0f - dx * csc, wx1 = 1.0f - (1.0f - dx) * csc;
    float sx = wx0 + wx1; wx0 /= sx; wx1 /= sx;
    float v = wy0 * (wx0 * a1 + wx1 * a2) + wy1 * (wx0 * b1 + wx1 * b2);
    n.y = 0.5f * ((v - mn) / (mx - mn));
  }
  {
    float dx = (float)(2 * (ox + 2) + 1) * (1.0f / 1024.0f);
    float wx0 = 1.0f - dx * csc, wx1 = 1.0f - (1.0f - dx) * csc;
    float sx = wx0 + wx1; wx0 /= sx; wx1 /= sx;
    float v = wy0 * (wx0 * a2 + wx1 * a3) + wy1 * (wx0 * b2 + wx1 * b3);
    n.z = 0.5f * ((v - mn) / (mx - mn));
  }
  {
    float dx = (float)(2 * (ox + 3) + 1) * (1.0f / 1024.0f);
    float wx0 = 1.0f - dx * csc, wx1 = 1.0f - (1.0f - dx) * csc;
    float sx = wx0 + wx1; wx0 /= sx; wx1 /= sx;
    float v = wy0 * (wx0 * a3 + wx1 * a4) + wy1 * (wx0 * b3 + wx1 * b4);
    n.w = 0.5f * ((v - mn) / (mx - mn));
  }
  float4 cn;  // 1 - n, precomputed for fma form
  cn.x = 1.0f - n.x; cn.y = 1.0f - n.y; cn.z = 1.0f - n.z; cn.w = 1.0f - n.w;

  int base = pg * (24 * 65536) + pos4;
#pragma unroll 4
  for (int p = 0; p < 24; ++p) {
    float4 a = img[base + p * 65536];
    float4 o;
    o.x = fminf(fmaxf(a.x * cn.x + n.x, 0.0f), 1.0f);
    o.y = fminf(fmaxf(a.y * cn.y + n.y, 0.0f), 1.0f);
    o.z = fminf(fmaxf(a.z * cn.z + n.z, 0.0f), 1.0f);
    o.w = fminf(fmaxf(a.w * cn.w + n.w, 0.0f), 1.0f);
    out[base + p * 65536] = o;
  }
}

extern "C" void kernel_launch(void* const* d_in, const int* in_sizes, int n_in,
                              void* d_out, int out_size, void* d_ws, size_t ws_size,
                              hipStream_t stream) {
  const float* img = (const float*)d_in[0];
  float* out = (float*)d_out;
  unsigned char* ws = (unsigned char*)d_ws;

  unsigned* mmx = (unsigned*)ws;
  float* hm = (float*)(ws + 16);

  // diamond-square + minmax in ONE cooperative dispatch
  void* args[] = {(void*)&hm, (void*)&mmx};
  hipError_t e = hipLaunchCooperativeKernel((const void*)k_ds_coop, dim3(256),
                                            dim3(256), args, 0, stream);
  if (e != hipSuccess) {
    // fallback: classic multi-kernel chain
    hipLaunchKernelGGL(k_ds_small, dim3(1), dim3(1024), 0, stream, hm, mmx);
    hipLaunchKernelGGL(k_level, dim3(16), dim3(256), 0, stream, hm, 6);
    hipLaunchKernelGGL(k_level, dim3(64), dim3(256), 0, stream, hm, 7);
    hipLaunchKernelGGL(k_level, dim3(256), dim3(256), 0, stream, hm, 8);
    hipLaunchKernelGGL(k_minmax, dim3(64), dim3(256), 0, stream, hm, mmx);
  }

  // fused noise + apply: 262144 threads, each covers one float4 pos x 24 planes
  hipLaunchKernelGGL(k_apply_fused, dim3(256), dim3(1024), 0, stream,
                     (const float4*)img, hm, mmx, (float4*)out);
}

// Round 2
// 242.376 us; speedup vs baseline: 1.8787x; 1.8787x over previous
//
#include <hip/hip_runtime.h>

// ---------------------------------------------------------------------------
// Threefry2x32 (JAX-compatible), usable at compile time (constexpr) and runtime
// PRNG layer assumes jax_threefry_partitionable=True (JAX >= 0.4.30 default):
//   fold_in(key,d)        = threefry(key,(0,d))            (both modes)
//   split(key,n)[m]       = threefry(key,(0,m))  full pair (foldlike)
//   random_bits(32)[i]    = v0 ^ v1 of threefry(key,(0,i)) (counter mode)
// ---------------------------------------------------------------------------
struct KP { unsigned a, b; };

__host__ __device__ constexpr unsigned rotl32(unsigned x, int d) {
  return (x << d) | (x >> (32 - d));
}

__host__ __device__ constexpr KP tf2x32(unsigned k0, unsigned k1, unsigned x0, unsigned x1) {
  unsigned k2 = k0 ^ k1 ^ 0x1BD11BDAu;
  unsigned v0 = x0 + k0;
  unsigned v1 = x1 + k1;
  const int R[5][4] = {{13,15,26,6},{17,29,16,24},{13,15,26,6},{17,29,16,24},{13,15,26,6}};
  const unsigned KI[5][2] = {{k1, k2 + 1u},{k2, k0 + 2u},{k0, k1 + 3u},{k1, k2 + 4u},{k2, k0 + 5u}};
  for (int g = 0; g < 5; ++g) {
    for (int r = 0; r < 4; ++r) {
      v0 += v1;
      v1 = rotl32(v1, R[g][r]);
      v1 ^= v0;
    }
    v0 += KI[g][0];
    v1 += KI[g][1];
  }
  return KP{v0, v1};
}

// Compile-time key schedule: root key (0,42); per-level fold_in + foldlike
// split(5); corner key fold_in(1000).
struct AllKeys {
  unsigned lk[9][5][2];   // [level][stream: centers,top,left,right,bottom][k0,k1]
  unsigned ck[2];         // corner key
};

__host__ __device__ constexpr AllKeys make_keys() {
  AllKeys K{};
  for (int l = 0; l < 9; ++l) {
    KP base = tf2x32(0u, 42u, 0u, (unsigned)l);          // fold_in(key, level)
    for (int m = 0; m < 5; ++m) {                        // foldlike split
      KP s = tf2x32(base.a, base.b, 0u, (unsigned)m);
      K.lk[l][m][0] = s.a;
      K.lk[l][m][1] = s.b;
    }
  }
  KP ck = tf2x32(0u, 42u, 0u, 1000u);                    // fold_in(key, 1000)
  K.ck[0] = ck.a;
  K.ck[1] = ck.b;
  return K;
}

constexpr AllKeys KEYS = make_keys();

#define NG 513

// partitionable random_bits(32): element i = v0 ^ v1 of cipher(key, (0, i))
__device__ inline unsigned rbits(unsigned k0, unsigned k1, unsigned i) {
  KP o = tf2x32(k0, k1, 0u, i);
  return o.a ^ o.b;
}

__device__ inline float bits_to_u(unsigned b, float r) {
  float u = __uint_as_float((b >> 9) | 0x3f800000u) - 1.0f;   // [0,1)
  return fmaxf(-r, u * (2.0f * r) - r);                       // uniform(-r, r)
}

__device__ inline float draw_u(const unsigned* kk, unsigned i, float r) {
  return bits_to_u(rbits(kk[0], kk[1], i), r);
}

// recompute center of cell (a,b) at given level (reads only coarser-level hm)
__device__ inline float cell_center(const float* hm, int level, int g, int L,
                                    int a, int b, float r) {
  int lo_i = a * L, hi_i = lo_i + L, lo_j = b * L, hi_j = lo_j + L;
  float nw = hm[lo_i * NG + lo_j], ne = hm[lo_i * NG + hi_j];
  float sw = hm[hi_i * NG + lo_j], se = hm[hi_i * NG + hi_j];
  return (nw + ne + sw + se) * 0.25f +
         draw_u(KEYS.lk[level][0], (unsigned)(a * g + b), r);
}

// Every hm point is written exactly once across all levels (the ==0 guards
// prevent rewrites), so accumulating min/max of written values is an EXACT
// global min/max — no separate full-grid pass needed.
__device__ inline void do_cell(float* hm, int level, int i, int j,
                               float& mnv, float& mxv) {
  int g = 1 << level;
  int L = 512 >> level;
  int h = L >> 1;
  float r = 1.0f / (float)(level + 1);
  int lo_i = i * L, hi_i = lo_i + L, mi_i = lo_i + h;
  int lo_j = j * L, hi_j = lo_j + L, mi_j = lo_j + h;
  float nw = hm[lo_i * NG + lo_j], ne = hm[lo_i * NG + hi_j];
  float sw = hm[hi_i * NG + lo_j], se = hm[hi_i * NG + hi_j];
  unsigned m = (unsigned)(i * g + j);

  float c = (nw + ne + sw + se) * 0.25f + draw_u(KEYS.lk[level][0], m, r);
  hm[mi_i * NG + mi_j] = c;
  mnv = fminf(mnv, c); mxv = fmaxf(mxv, c);

  // right edge midpoint (temp_r: own center, wraps to column 0 on last column)
  float tr = (j < g - 1) ? c : cell_center(hm, level, g, L, i, 0, r);
  float right = (c + ne + se + tr) * 0.25f + draw_u(KEYS.lk[level][3], m, r);
  hm[mi_i * NG + hi_j] = right;
  mnv = fminf(mnv, right); mxv = fmaxf(mxv, right);

  // bottom edge midpoint (temp_b: own center, wraps to row 0 on last row)
  float tb = (i < g - 1) ? c : cell_center(hm, level, g, L, 0, j, r);
  float bottom = (c + sw + se + tb) * 0.25f + draw_u(KEYS.lk[level][4], m, r);
  hm[hi_i * NG + mi_j] = bottom;
  mnv = fminf(mnv, bottom); mxv = fmaxf(mxv, bottom);

  if (i == 0) {  // top row midpoints
    float cg1 = (g == 1) ? c : cell_center(hm, level, g, L, g - 1, j, r);
    float top = (c + hm[lo_j] + hm[hi_j] + cg1) * 0.25f +
                draw_u(KEYS.lk[level][1], (unsigned)j, r);
    hm[mi_j] = top;
    mnv = fminf(mnv, top); mxv = fmaxf(mxv, top);
  }
  if (j == 0) {  // left column midpoints
    float cg1 = (g == 1) ? c : cell_center(hm, level, g, L, i, g - 1, r);
    float left = (c + hm[lo_i * NG] + hm[hi_i * NG] + cg1) * 0.25f +
                 draw_u(KEYS.lk[level][2], (unsigned)i, r);
    hm[mi_i * NG] = left;
    mnv = fminf(mnv, left); mxv = fmaxf(mxv, left);
  }
}

__device__ inline unsigned enc_f(float f) {
  unsigned u = __float_as_uint(f);
  return (u & 0x80000000u) ? ~u : (u | 0x80000000u);
}
__device__ inline float dec_f(unsigned e) {
  unsigned u = (e & 0x80000000u) ? (e & 0x7FFFFFFFu) : ~e;
  return __uint_as_float(u);
}

// wave-reduce local min/max, then one atomic pair per wave
__device__ inline void mmx_commit(unsigned* mmx, float mn, float mx, int tid) {
#pragma unroll
  for (int off = 32; off >= 1; off >>= 1) {
    mn = fminf(mn, __shfl_down(mn, off, 64));
    mx = fmaxf(mx, __shfl_down(mx, off, 64));
  }
  if ((tid & 63) == 0) {
    atomicMin(&mmx[0], enc_f(mn));
    atomicMax(&mmx[1], enc_f(mx));
  }
}

// corners + levels 0..5 in one block (<=1024 cells per level), minmax fused
__global__ void k_ds_small(float* hm, unsigned* mmx) {
  int tid = threadIdx.x;
  float mn = 3.4e38f, mx = -3.4e38f;
  if (tid == 0) {
#pragma unroll
    for (int q = 0; q < 4; ++q) {
      float v = bits_to_u(rbits(KEYS.ck[0], KEYS.ck[1], (unsigned)q), 1.0f);
      int y = (q >> 1) ? 512 : 0;
      int x = (q & 1) ? 512 : 0;
      hm[y * NG + x] = v;
      mn = fminf(mn, v); mx = fmaxf(mx, v);
    }
    mmx[0] = 0xFFFFFFFFu;  // min slot (atomicMin target)
    mmx[1] = 0u;           // max slot (atomicMax target)
  }
  __syncthreads();
  for (int lvl = 0; lvl <= 5; ++lvl) {
    int g = 1 << lvl;
    if (tid < g * g) do_cell(hm, lvl, tid >> lvl, tid & (g - 1), mn, mx);
    __syncthreads();
  }
  mmx_commit(mmx, mn, mx, tid);
}

__global__ void k_level(float* hm, unsigned* mmx, int level) {
  int g = 1 << level;
  int gt = blockIdx.x * blockDim.x + threadIdx.x;
  float mn = 3.4e38f, mx = -3.4e38f;
  do_cell(hm, level, gt >> level, gt & (g - 1), mn, mx);
  mmx_commit(mmx, mn, mx, (int)threadIdx.x);
}

// ---------------------------------------------------------------------------
// Fused noise + apply: each thread owns ONE float4 pixel position, computes
// the bilinear-resized normalized noise once, and streams it across 24 of
// the 96 planes (4 thread-groups cover all planes). rn never hits memory.
// out = clip(img*(1-rn) + rn, 0, 1)
// ---------------------------------------------------------------------------
__global__ void __launch_bounds__(1024) k_apply_fused(
    const float4* __restrict__ img, const float* __restrict__ hm,
    const unsigned* __restrict__ mmx, float4* __restrict__ out) {
  int t = blockIdx.x * 1024 + threadIdx.x;   // 0..262143
  int pos4 = t & 65535;                      // within-plane float4 index
  int pg = t >> 16;                          // plane group 0..3 (24 planes each)
  int oy = pos4 >> 7;                        // 128 float4 per row
  int ox = (pos4 & 127) << 2;

  // exact two-tap triangle weights: kernel_scale = 513/512
  const float csc = 512.0f / 513.0f;
  float dy = (float)(2 * oy + 1) * (1.0f / 1024.0f);
  float wy0 = 1.0f - dy * csc;
  float wy1 = 1.0f - (1.0f - dy) * csc;
  float sy = wy0 + wy1;
  wy0 /= sy; wy1 /= sy;

  const float* r0 = hm + oy * NG + ox;
  const float* r1 = r0 + NG;
  float a0 = r0[0], a1 = r0[1], a2 = r0[2], a3 = r0[3], a4 = r0[4];
  float b0 = r1[0], b1 = r1[1], b2 = r1[2], b3 = r1[3], b4 = r1[4];

  float mn = dec_f(mmx[0]), mx = dec_f(mmx[1]);

  float4 n;
  {
    float dx = (float)(2 * ox + 1) * (1.0f / 1024.0f);
    float wx0 = 1.0f - dx * csc, wx1 = 1.0f - (1.0f - dx) * csc;
    float sx = wx0 + wx1; wx0 /= sx; wx1 /= sx;
    float v = wy0 * (wx0 * a0 + wx1 * a1) + wy1 * (wx0 * b0 + wx1 * b1);
    n.x = 0.5f * ((v - mn) / (mx - mn));
  }
  {
    float dx = (float)(2 * (ox + 1) + 1) * (1.0f / 1024.0f);
    float wx0 = 1.0f - dx * csc, wx1 = 1.0f - (1.0f - dx) * csc;
    float sx = wx0 + wx1; wx0 /= sx; wx1 /= sx;
    float v = wy0 * (wx0 * a1 + wx1 * a2) + wy1 * (wx0 * b1 + wx1 * b2);
    n.y = 0.5f * ((v - mn) / (mx - mn));
  }
  {
    float dx = (float)(2 * (ox + 2) + 1) * (1.0f / 1024.0f);
    float wx0 = 1.0f - dx * csc, wx1 = 1.0f - (1.0f - dx) * csc;
    float sx = wx0 + wx1; wx0 /= sx; wx1 /= sx;
    float v = wy0 * (wx0 * a2 + wx1 * a3) + wy1 * (wx0 * b2 + wx1 * b3);
    n.z = 0.5f * ((v - mn) / (mx - mn));
  }
  {
    float dx = (float)(2 * (ox + 3) + 1) * (1.0f / 1024.0f);
    float wx0 = 1.0f - dx * csc, wx1 = 1.0f - (1.0f - dx) * csc;
    float sx = wx0 + wx1; wx0 /= sx; wx1 /= sx;
    float v = wy0 * (wx0 * a3 + wx1 * a4) + wy1 * (wx0 * b3 + wx1 * b4);
    n.w = 0.5f * ((v - mn) / (mx - mn));
  }
  float4 cn;  // 1 - n, precomputed for fma form
  cn.x = 1.0f - n.x; cn.y = 1.0f - n.y; cn.z = 1.0f - n.z; cn.w = 1.0f - n.w;

  int base = pg * (24 * 65536) + pos4;
#pragma unroll 4
  for (int p = 0; p < 24; ++p) {
    float4 a = img[base + p * 65536];
    float4 o;
    o.x = fminf(fmaxf(a.x * cn.x + n.x, 0.0f), 1.0f);
    o.y = fminf(fmaxf(a.y * cn.y + n.y, 0.0f), 1.0f);
    o.z = fminf(fmaxf(a.z * cn.z + n.z, 0.0f), 1.0f);
    o.w = fminf(fmaxf(a.w * cn.w + n.w, 0.0f), 1.0f);
    out[base + p * 65536] = o;
  }
}

extern "C" void kernel_launch(void* const* d_in, const int* in_sizes, int n_in,
                              void* d_out, int out_size, void* d_ws, size_t ws_size,
                              hipStream_t stream) {
  const float* img = (const float*)d_in[0];
  float* out = (float*)d_out;
  unsigned char* ws = (unsigned char*)d_ws;

  unsigned* mmx = (unsigned*)ws;
  float* hm = (float*)(ws + 16);

  // diamond-square with fused exact minmax: 4 dispatches, no grid.sync
  hipLaunchKernelGGL(k_ds_small, dim3(1), dim3(1024), 0, stream, hm, mmx);
  hipLaunchKernelGGL(k_level, dim3(16), dim3(256), 0, stream, hm, mmx, 6);
  hipLaunchKernelGGL(k_level, dim3(64), dim3(256), 0, stream, hm, mmx, 7);
  hipLaunchKernelGGL(k_level, dim3(256), dim3(256), 0, stream, hm, mmx, 8);

  // fused noise + apply: 262144 threads, each covers one float4 pos x 24 planes
  hipLaunchKernelGGL(k_apply_fused, dim3(256), dim3(1024), 0, stream,
                     (const float4*)img, hm, mmx, (float4*)out);
}

// Round 3
// 237.530 us; speedup vs baseline: 1.9170x; 1.0204x over previous
//
#include <hip/hip_runtime.h>

// ---------------------------------------------------------------------------
// Threefry2x32 (JAX-compatible), usable at compile time (constexpr) and runtime
// PRNG layer assumes jax_threefry_partitionable=True (JAX >= 0.4.30 default):
//   fold_in(key,d)        = threefry(key,(0,d))            (both modes)
//   split(key,n)[m]       = threefry(key,(0,m))  full pair (foldlike)
//   random_bits(32)[i]    = v0 ^ v1 of threefry(key,(0,i)) (counter mode)
// ---------------------------------------------------------------------------
struct KP { unsigned a, b; };

__host__ __device__ constexpr unsigned rotl32(unsigned x, int d) {
  return (x << d) | (x >> (32 - d));
}

__host__ __device__ constexpr KP tf2x32(unsigned k0, unsigned k1, unsigned x0, unsigned x1) {
  unsigned k2 = k0 ^ k1 ^ 0x1BD11BDAu;
  unsigned v0 = x0 + k0;
  unsigned v1 = x1 + k1;
  const int R[5][4] = {{13,15,26,6},{17,29,16,24},{13,15,26,6},{17,29,16,24},{13,15,26,6}};
  const unsigned KI[5][2] = {{k1, k2 + 1u},{k2, k0 + 2u},{k0, k1 + 3u},{k1, k2 + 4u},{k2, k0 + 5u}};
  for (int g = 0; g < 5; ++g) {
    for (int r = 0; r < 4; ++r) {
      v0 += v1;
      v1 = rotl32(v1, R[g][r]);
      v1 ^= v0;
    }
    v0 += KI[g][0];
    v1 += KI[g][1];
  }
  return KP{v0, v1};
}

// Compile-time key schedule: root key (0,42); per-level fold_in + foldlike
// split(5); corner key fold_in(1000).
struct AllKeys {
  unsigned lk[9][5][2];   // [level][stream: centers,top,left,right,bottom][k0,k1]
  unsigned ck[2];         // corner key
};

__host__ __device__ constexpr AllKeys make_keys() {
  AllKeys K{};
  for (int l = 0; l < 9; ++l) {
    KP base = tf2x32(0u, 42u, 0u, (unsigned)l);          // fold_in(key, level)
    for (int m = 0; m < 5; ++m) {                        // foldlike split
      KP s = tf2x32(base.a, base.b, 0u, (unsigned)m);
      K.lk[l][m][0] = s.a;
      K.lk[l][m][1] = s.b;
    }
  }
  KP ck = tf2x32(0u, 42u, 0u, 1000u);                    // fold_in(key, 1000)
  K.ck[0] = ck.a;
  K.ck[1] = ck.b;
  return K;
}

constexpr AllKeys KEYS = make_keys();

#define NG 513

// partitionable random_bits(32): element i = v0 ^ v1 of cipher(key, (0, i))
__device__ inline unsigned rbits(unsigned k0, unsigned k1, unsigned i) {
  KP o = tf2x32(k0, k1, 0u, i);
  return o.a ^ o.b;
}

__device__ inline float bits_to_u(unsigned b, float r) {
  float u = __uint_as_float((b >> 9) | 0x3f800000u) - 1.0f;   // [0,1)
  return fmaxf(-r, u * (2.0f * r) - r);                       // uniform(-r, r)
}

__device__ inline float draw_u(const unsigned* kk, unsigned i, float r) {
  return bits_to_u(rbits(kk[0], kk[1], i), r);
}

// recompute center of cell (a,b) at given level (reads only coarser-level hm)
__device__ inline float cell_center(const float* hm, int level, int g, int L,
                                    int a, int b, float r) {
  int lo_i = a * L, hi_i = lo_i + L, lo_j = b * L, hi_j = lo_j + L;
  float nw = hm[lo_i * NG + lo_j], ne = hm[lo_i * NG + hi_j];
  float sw = hm[hi_i * NG + lo_j], se = hm[hi_i * NG + hi_j];
  return (nw + ne + sw + se) * 0.25f +
         draw_u(KEYS.lk[level][0], (unsigned)(a * g + b), r);
}

// Every hm point is written exactly once across all levels (the ==0 guards
// prevent rewrites), so accumulating min/max of written values is an EXACT
// global min/max — no separate full-grid pass needed.
__device__ inline void do_cell(float* hm, int level, int i, int j,
                               float& mnv, float& mxv) {
  int g = 1 << level;
  int L = 512 >> level;
  int h = L >> 1;
  float r = 1.0f / (float)(level + 1);
  int lo_i = i * L, hi_i = lo_i + L, mi_i = lo_i + h;
  int lo_j = j * L, hi_j = lo_j + L, mi_j = lo_j + h;
  float nw = hm[lo_i * NG + lo_j], ne = hm[lo_i * NG + hi_j];
  float sw = hm[hi_i * NG + lo_j], se = hm[hi_i * NG + hi_j];
  unsigned m = (unsigned)(i * g + j);

  float c = (nw + ne + sw + se) * 0.25f + draw_u(KEYS.lk[level][0], m, r);
  hm[mi_i * NG + mi_j] = c;
  mnv = fminf(mnv, c); mxv = fmaxf(mxv, c);

  // right edge midpoint (temp_r: own center, wraps to column 0 on last column)
  float tr = (j < g - 1) ? c : cell_center(hm, level, g, L, i, 0, r);
  float right = (c + ne + se + tr) * 0.25f + draw_u(KEYS.lk[level][3], m, r);
  hm[mi_i * NG + hi_j] = right;
  mnv = fminf(mnv, right); mxv = fmaxf(mxv, right);

  // bottom edge midpoint (temp_b: own center, wraps to row 0 on last row)
  float tb = (i < g - 1) ? c : cell_center(hm, level, g, L, 0, j, r);
  float bottom = (c + sw + se + tb) * 0.25f + draw_u(KEYS.lk[level][4], m, r);
  hm[hi_i * NG + mi_j] = bottom;
  mnv = fminf(mnv, bottom); mxv = fmaxf(mxv, bottom);

  if (i == 0) {  // top row midpoints
    float cg1 = (g == 1) ? c : cell_center(hm, level, g, L, g - 1, j, r);
    float top = (c + hm[lo_j] + hm[hi_j] + cg1) * 0.25f +
                draw_u(KEYS.lk[level][1], (unsigned)j, r);
    hm[mi_j] = top;
    mnv = fminf(mnv, top); mxv = fmaxf(mxv, top);
  }
  if (j == 0) {  // left column midpoints
    float cg1 = (g == 1) ? c : cell_center(hm, level, g, L, i, g - 1, r);
    float left = (c + hm[lo_i * NG] + hm[hi_i * NG] + cg1) * 0.25f +
                 draw_u(KEYS.lk[level][2], (unsigned)i, r);
    hm[mi_i * NG] = left;
    mnv = fminf(mnv, left); mxv = fmaxf(mxv, left);
  }
}

__device__ inline unsigned enc_f(float f) {
  unsigned u = __float_as_uint(f);
  return (u & 0x80000000u) ? ~u : (u | 0x80000000u);
}
__device__ inline float dec_f(unsigned e) {
  unsigned u = (e & 0x80000000u) ? (e & 0x7FFFFFFFu) : ~e;
  return __uint_as_float(u);
}

// wave-reduce local min/max, then one atomic pair per wave
__device__ inline void mmx_commit(unsigned* mmx, float mn, float mx, int tid) {
#pragma unroll
  for (int off = 32; off >= 1; off >>= 1) {
    mn = fminf(mn, __shfl_down(mn, off, 64));
    mx = fmaxf(mx, __shfl_down(mx, off, 64));
  }
  if ((tid & 63) == 0) {
    atomicMin(&mmx[0], enc_f(mn));
    atomicMax(&mmx[1], enc_f(mx));
  }
}

// corners + levels 0..5 in one block (<=1024 cells per level), minmax fused
__global__ void k_ds_small(float* hm, unsigned* mmx) {
  int tid = threadIdx.x;
  float mn = 3.4e38f, mx = -3.4e38f;
  if (tid == 0) {
#pragma unroll
    for (int q = 0; q < 4; ++q) {
      float v = bits_to_u(rbits(KEYS.ck[0], KEYS.ck[1], (unsigned)q), 1.0f);
      int y = (q >> 1) ? 512 : 0;
      int x = (q & 1) ? 512 : 0;
      hm[y * NG + x] = v;
      mn = fminf(mn, v); mx = fmaxf(mx, v);
    }
    mmx[0] = 0xFFFFFFFFu;  // min slot (atomicMin target)
    mmx[1] = 0u;           // max slot (atomicMax target)
  }
  __syncthreads();
  for (int lvl = 0; lvl <= 5; ++lvl) {
    int g = 1 << lvl;
    if (tid < g * g) do_cell(hm, lvl, tid >> lvl, tid & (g - 1), mn, mx);
    __syncthreads();
  }
  mmx_commit(mmx, mn, mx, tid);
}

__global__ void k_level(float* hm, unsigned* mmx, int level) {
  int g = 1 << level;
  int gt = blockIdx.x * blockDim.x + threadIdx.x;
  float mn = 3.4e38f, mx = -3.4e38f;
  do_cell(hm, level, gt >> level, gt & (g - 1), mn, mx);
  mmx_commit(mmx, mn, mx, (int)threadIdx.x);
}

// ---------------------------------------------------------------------------
// Fused noise + apply: each thread owns ONE float4 pixel position, computes
// the bilinear-resized normalized noise once, and streams it across 4 planes
// (24 thread-groups cover all 96 planes). rn never hits memory.
// Grid: 6144 blocks x 256 thr = 1.57M threads -> 24 queued blocks/CU,
// 8 resident blocks/CU (32 waves/CU) — full TLP for latency hiding,
// unlike the 24-plane version (256 blocks, 16 waves/CU, 2.4 TB/s).
// out = clip(img*(1-rn) + rn, 0, 1)
// ---------------------------------------------------------------------------
#define PPT 4   // planes per thread (96 planes / PPT = 24 groups)
__global__ void __launch_bounds__(256) k_apply_fused(
    const float4* __restrict__ img, const float* __restrict__ hm,
    const unsigned* __restrict__ mmx, float4* __restrict__ out) {
  int t = blockIdx.x * 256 + threadIdx.x;    // 0 .. 1572863
  int pos4 = t & 65535;                      // within-plane float4 index
  int pg = t >> 16;                          // plane group 0..23 (PPT planes each)
  int oy = pos4 >> 7;                        // 128 float4 per row
  int ox = (pos4 & 127) << 2;

  // exact two-tap triangle weights: kernel_scale = 513/512
  const float csc = 512.0f / 513.0f;
  float dy = (float)(2 * oy + 1) * (1.0f / 1024.0f);
  float wy0 = 1.0f - dy * csc;
  float wy1 = 1.0f - (1.0f - dy) * csc;
  float sy = wy0 + wy1;
  wy0 /= sy; wy1 /= sy;

  const float* r0 = hm + oy * NG + ox;
  const float* r1 = r0 + NG;
  float a0 = r0[0], a1 = r0[1], a2 = r0[2], a3 = r0[3], a4 = r0[4];
  float b0 = r1[0], b1 = r1[1], b2 = r1[2], b3 = r1[3], b4 = r1[4];

  float mn = dec_f(mmx[0]), mx = dec_f(mmx[1]);

  float4 n;
  {
    float dx = (float)(2 * ox + 1) * (1.0f / 1024.0f);
    float wx0 = 1.0f - dx * csc, wx1 = 1.0f - (1.0f - dx) * csc;
    float sx = wx0 + wx1; wx0 /= sx; wx1 /= sx;
    float v = wy0 * (wx0 * a0 + wx1 * a1) + wy1 * (wx0 * b0 + wx1 * b1);
    n.x = 0.5f * ((v - mn) / (mx - mn));
  }
  {
    float dx = (float)(2 * (ox + 1) + 1) * (1.0f / 1024.0f);
    float wx0 = 1.0f - dx * csc, wx1 = 1.0f - (1.0f - dx) * csc;
    float sx = wx0 + wx1; wx0 /= sx; wx1 /= sx;
    float v = wy0 * (wx0 * a1 + wx1 * a2) + wy1 * (wx0 * b1 + wx1 * b2);
    n.y = 0.5f * ((v - mn) / (mx - mn));
  }
  {
    float dx = (float)(2 * (ox + 2) + 1) * (1.0f / 1024.0f);
    float wx0 = 1.0f - dx * csc, wx1 = 1.0f - (1.0f - dx) * csc;
    float sx = wx0 + wx1; wx0 /= sx; wx1 /= sx;
    float v = wy0 * (wx0 * a2 + wx1 * a3) + wy1 * (wx0 * b2 + wx1 * b3);
    n.z = 0.5f * ((v - mn) / (mx - mn));
  }
  {
    float dx = (float)(2 * (ox + 3) + 1) * (1.0f / 1024.0f);
    float wx0 = 1.0f - dx * csc, wx1 = 1.0f - (1.0f - dx) * csc;
    float sx = wx0 + wx1; wx0 /= sx; wx1 /= sx;
    float v = wy0 * (wx0 * a3 + wx1 * a4) + wy1 * (wx0 * b3 + wx1 * b4);
    n.w = 0.5f * ((v - mn) / (mx - mn));
  }
  float4 cn;  // 1 - n, precomputed for fma form
  cn.x = 1.0f - n.x; cn.y = 1.0f - n.y; cn.z = 1.0f - n.z; cn.w = 1.0f - n.w;

  int base = pg * (PPT * 65536) + pos4;
#pragma unroll
  for (int p = 0; p < PPT; ++p) {
    float4 a = img[base + p * 65536];
    float4 o;
    o.x = fminf(fmaxf(a.x * cn.x + n.x, 0.0f), 1.0f);
    o.y = fminf(fmaxf(a.y * cn.y + n.y, 0.0f), 1.0f);
    o.z = fminf(fmaxf(a.z * cn.z + n.z, 0.0f), 1.0f);
    o.w = fminf(fmaxf(a.w * cn.w + n.w, 0.0f), 1.0f);
    out[base + p * 65536] = o;
  }
}

extern "C" void kernel_launch(void* const* d_in, const int* in_sizes, int n_in,
                              void* d_out, int out_size, void* d_ws, size_t ws_size,
                              hipStream_t stream) {
  const float* img = (const float*)d_in[0];
  float* out = (float*)d_out;
  unsigned char* ws = (unsigned char*)d_ws;

  unsigned* mmx = (unsigned*)ws;
  float* hm = (float*)(ws + 16);

  // diamond-square with fused exact minmax: 4 dispatches, no grid.sync
  hipLaunchKernelGGL(k_ds_small, dim3(1), dim3(1024), 0, stream, hm, mmx);
  hipLaunchKernelGGL(k_level, dim3(16), dim3(256), 0, stream, hm, mmx, 6);
  hipLaunchKernelGGL(k_level, dim3(64), dim3(256), 0, stream, hm, mmx, 7);
  hipLaunchKernelGGL(k_level, dim3(256), dim3(256), 0, stream, hm, mmx, 8);

  // fused noise + apply: 1.57M threads, each covers one float4 pos x 4 planes
  hipLaunchKernelGGL(k_apply_fused, dim3(32 * 3 * 512 * 512 / 4 / PPT / 256),
                     dim3(256), 0, stream,
                     (const float4*)img, hm, mmx, (float4*)out);
}

// Round 4
// 233.251 us; speedup vs baseline: 1.9522x; 1.0183x over previous
//
#include <hip/hip_runtime.h>

// ---------------------------------------------------------------------------
// Threefry2x32 (JAX-compatible), usable at compile time (constexpr) and runtime
// PRNG layer assumes jax_threefry_partitionable=True (JAX >= 0.4.30 default):
//   fold_in(key,d)        = threefry(key,(0,d))            (both modes)
//   split(key,n)[m]       = threefry(key,(0,m))  full pair (foldlike)
//   random_bits(32)[i]    = v0 ^ v1 of threefry(key,(0,i)) (counter mode)
// ---------------------------------------------------------------------------
struct KP { unsigned a, b; };

__host__ __device__ constexpr unsigned rotl32(unsigned x, int d) {
  return (x << d) | (x >> (32 - d));
}

__host__ __device__ constexpr KP tf2x32(unsigned k0, unsigned k1, unsigned x0, unsigned x1) {
  unsigned k2 = k0 ^ k1 ^ 0x1BD11BDAu;
  unsigned v0 = x0 + k0;
  unsigned v1 = x1 + k1;
  const int R[5][4] = {{13,15,26,6},{17,29,16,24},{13,15,26,6},{17,29,16,24},{13,15,26,6}};
  const unsigned KI[5][2] = {{k1, k2 + 1u},{k2, k0 + 2u},{k0, k1 + 3u},{k1, k2 + 4u},{k2, k0 + 5u}};
  for (int g = 0; g < 5; ++g) {
    for (int r = 0; r < 4; ++r) {
      v0 += v1;
      v1 = rotl32(v1, R[g][r]);
      v1 ^= v0;
    }
    v0 += KI[g][0];
    v1 += KI[g][1];
  }
  return KP{v0, v1};
}

// Compile-time key schedule: root key (0,42); per-level fold_in + foldlike
// split(5); corner key fold_in(1000).
struct AllKeys {
  unsigned lk[9][5][2];   // [level][stream: centers,top,left,right,bottom][k0,k1]
  unsigned ck[2];         // corner key
};

__host__ __device__ constexpr AllKeys make_keys() {
  AllKeys K{};
  for (int l = 0; l < 9; ++l) {
    KP base = tf2x32(0u, 42u, 0u, (unsigned)l);          // fold_in(key, level)
    for (int m = 0; m < 5; ++m) {                        // foldlike split
      KP s = tf2x32(base.a, base.b, 0u, (unsigned)m);
      K.lk[l][m][0] = s.a;
      K.lk[l][m][1] = s.b;
    }
  }
  KP ck = tf2x32(0u, 42u, 0u, 1000u);                    // fold_in(key, 1000)
  K.ck[0] = ck.a;
  K.ck[1] = ck.b;
  return K;
}

constexpr AllKeys KEYS = make_keys();

#define NG 513

// partitionable random_bits(32): element i = v0 ^ v1 of cipher(key, (0, i))
__device__ inline unsigned rbits(unsigned k0, unsigned k1, unsigned i) {
  KP o = tf2x32(k0, k1, 0u, i);
  return o.a ^ o.b;
}

__device__ inline float bits_to_u(unsigned b, float r) {
  float u = __uint_as_float((b >> 9) | 0x3f800000u) - 1.0f;   // [0,1)
  return fmaxf(-r, u * (2.0f * r) - r);                       // uniform(-r, r)
}

__device__ inline float draw_u(const unsigned* kk, unsigned i, float r) {
  return bits_to_u(rbits(kk[0], kk[1], i), r);
}

// recompute center of cell (a,b) at given level (reads only coarser-level hm)
__device__ inline float cell_center(const float* hm, int level, int g, int L,
                                    int a, int b, float r) {
  int lo_i = a * L, hi_i = lo_i + L, lo_j = b * L, hi_j = lo_j + L;
  float nw = hm[lo_i * NG + lo_j], ne = hm[lo_i * NG + hi_j];
  float sw = hm[hi_i * NG + lo_j], se = hm[hi_i * NG + hi_j];
  return (nw + ne + sw + se) * 0.25f +
         draw_u(KEYS.lk[level][0], (unsigned)(a * g + b), r);
}

// Every hm point is written exactly once across all levels (the ==0 guards
// prevent rewrites), so accumulating min/max of written values is an EXACT
// global min/max — no separate full-grid pass needed.
__device__ inline void do_cell(float* hm, int level, int i, int j,
                               float& mnv, float& mxv) {
  int g = 1 << level;
  int L = 512 >> level;
  int h = L >> 1;
  float r = 1.0f / (float)(level + 1);
  int lo_i = i * L, hi_i = lo_i + L, mi_i = lo_i + h;
  int lo_j = j * L, hi_j = lo_j + L, mi_j = lo_j + h;
  float nw = hm[lo_i * NG + lo_j], ne = hm[lo_i * NG + hi_j];
  float sw = hm[hi_i * NG + lo_j], se = hm[hi_i * NG + hi_j];
  unsigned m = (unsigned)(i * g + j);

  float c = (nw + ne + sw + se) * 0.25f + draw_u(KEYS.lk[level][0], m, r);
  hm[mi_i * NG + mi_j] = c;
  mnv = fminf(mnv, c); mxv = fmaxf(mxv, c);

  // right edge midpoint (temp_r: own center, wraps to column 0 on last column)
  float tr = (j < g - 1) ? c : cell_center(hm, level, g, L, i, 0, r);
  float right = (c + ne + se + tr) * 0.25f + draw_u(KEYS.lk[level][3], m, r);
  hm[mi_i * NG + hi_j] = right;
  mnv = fminf(mnv, right); mxv = fmaxf(mxv, right);

  // bottom edge midpoint (temp_b: own center, wraps to row 0 on last row)
  float tb = (i < g - 1) ? c : cell_center(hm, level, g, L, 0, j, r);
  float bottom = (c + sw + se + tb) * 0.25f + draw_u(KEYS.lk[level][4], m, r);
  hm[hi_i * NG + mi_j] = bottom;
  mnv = fminf(mnv, bottom); mxv = fmaxf(mxv, bottom);

  if (i == 0) {  // top row midpoints
    float cg1 = (g == 1) ? c : cell_center(hm, level, g, L, g - 1, j, r);
    float top = (c + hm[lo_j] + hm[hi_j] + cg1) * 0.25f +
                draw_u(KEYS.lk[level][1], (unsigned)j, r);
    hm[mi_j] = top;
    mnv = fminf(mnv, top); mxv = fmaxf(mxv, top);
  }
  if (j == 0) {  // left column midpoints
    float cg1 = (g == 1) ? c : cell_center(hm, level, g, L, i, g - 1, r);
    float left = (c + hm[lo_i * NG] + hm[hi_i * NG] + cg1) * 0.25f +
                 draw_u(KEYS.lk[level][2], (unsigned)i, r);
    hm[mi_i * NG] = left;
    mnv = fminf(mnv, left); mxv = fmaxf(mxv, left);
  }
}

__device__ inline unsigned enc_f(float f) {
  unsigned u = __float_as_uint(f);
  return (u & 0x80000000u) ? ~u : (u | 0x80000000u);
}
__device__ inline float dec_f(unsigned e) {
  unsigned u = (e & 0x80000000u) ? (e & 0x7FFFFFFFu) : ~e;
  return __uint_as_float(u);
}

// wave-reduce local min/max, then one atomic pair per wave
__device__ inline void mmx_commit(unsigned* mmx, float mn, float mx, int tid) {
#pragma unroll
  for (int off = 32; off >= 1; off >>= 1) {
    mn = fminf(mn, __shfl_down(mn, off, 64));
    mx = fmaxf(mx, __shfl_down(mx, off, 64));
  }
  if ((tid & 63) == 0) {
    atomicMin(&mmx[0], enc_f(mn));
    atomicMax(&mmx[1], enc_f(mx));
  }
}

// corners + levels 0..5 in one block (<=1024 cells per level), minmax fused
__global__ void k_ds_small(float* hm, unsigned* mmx) {
  int tid = threadIdx.x;
  float mn = 3.4e38f, mx = -3.4e38f;
  if (tid == 0) {
#pragma unroll
    for (int q = 0; q < 4; ++q) {
      float v = bits_to_u(rbits(KEYS.ck[0], KEYS.ck[1], (unsigned)q), 1.0f);
      int y = (q >> 1) ? 512 : 0;
      int x = (q & 1) ? 512 : 0;
      hm[y * NG + x] = v;
      mn = fminf(mn, v); mx = fmaxf(mx, v);
    }
    mmx[0] = 0xFFFFFFFFu;  // min slot (atomicMin target)
    mmx[1] = 0u;           // max slot (atomicMax target)
  }
  __syncthreads();
  for (int lvl = 0; lvl <= 5; ++lvl) {
    int g = 1 << lvl;
    if (tid < g * g) do_cell(hm, lvl, tid >> lvl, tid & (g - 1), mn, mx);
    __syncthreads();
  }
  mmx_commit(mmx, mn, mx, tid);
}

__global__ void k_level(float* hm, unsigned* mmx, int level) {
  int g = 1 << level;
  int gt = blockIdx.x * blockDim.x + threadIdx.x;
  float mn = 3.4e38f, mx = -3.4e38f;
  do_cell(hm, level, gt >> level, gt & (g - 1), mn, mx);
  mmx_commit(mmx, mn, mx, (int)threadIdx.x);
}

// ---------------------------------------------------------------------------
// Fused noise + apply, division-free weights.
// KEY ALGEBRA: the two-tap triangle weight sum is CONSTANT:
//   sx = (1 - dx*csc) + (1 - (1-dx)*csc) = 2 - csc = 514/513  (no clamping at
//   513->512, both taps always positive), so wx0n = wx0 * 513/514 and
//   wx1n = 1 - wx0n. This removes 10 of the 14 per-thread FP divisions; the
//   normalize folds into one division (s = 0.5/(mx-mn)) + FMA (n = v*s - mn*s).
//   Round-3 evidence: 14 div-macros formed a ~300-cy serial chain gating every
//   store -> 59 us @ 2.5 TB/s, VALUBusy 17%.
// img loads are hoisted above the noise math so stores are the only consumers.
// Grid: PPT=2 planes/thread -> 12288 blocks x 256 (48 queued blocks/CU).
// ---------------------------------------------------------------------------
#define PPT 2   // planes per thread (96 planes / PPT = 48 groups)
__global__ void __launch_bounds__(256) k_apply_fused(
    const float4* __restrict__ img, const float* __restrict__ hm,
    const unsigned* __restrict__ mmx, float4* __restrict__ out) {
  int t = blockIdx.x * 256 + threadIdx.x;    // 0 .. 3145727
  int pos4 = t & 65535;                      // within-plane float4 index
  int pg = t >> 16;                          // plane group 0..47 (PPT planes each)
  int oy = pos4 >> 7;                        // 128 float4 per row
  int ox = (pos4 & 127) << 2;

  // hoist the streaming loads: independent of all noise math
  int base = pg * (PPT * 65536) + pos4;
  float4 A0 = img[base];
  float4 A1 = img[base + 65536];

  const float csc = 512.0f / 513.0f;     // kernel scale
  const float SXI = 513.0f / 514.0f;     // 1 / (2 - csc): constant weight norm

  // hm taps (L2-resident) — issue before the dependent math
  const float* r0 = hm + oy * NG + ox;
  const float* r1 = r0 + NG;
  float a0 = r0[0], a1 = r0[1], a2 = r0[2], a3 = r0[3], a4 = r0[4];
  float b0 = r1[0], b1 = r1[1], b2 = r1[2], b3 = r1[3], b4 = r1[4];
  float mn = dec_f(mmx[0]), mx = dec_f(mmx[1]);

  // the single remaining division (latency hidden under the tap loads)
  float s = 0.5f / (mx - mn);
  float c0 = -mn * s;                    // n = v*s + c0

  float dy = (float)(2 * oy + 1) * (1.0f / 1024.0f);
  float wy0 = (1.0f - dy * csc) * SXI;   // normalized; wy1n = 1 - wy0

  float dx0 = (float)(2 * ox + 1) * (1.0f / 1024.0f);
  const float DXS = 1.0f / 512.0f;       // dx step per component

  float4 n;
  {
    float w = (1.0f - dx0 * csc) * SXI;
    float rA = a1 + w * (a0 - a1);       // x-interp row0
    float rB = b1 + w * (b0 - b1);       // x-interp row1
    float v = rB + wy0 * (rA - rB);      // y-interp
    n.x = v * s + c0;
  }
  {
    float w = (1.0f - (dx0 + DXS) * csc) * SXI;
    float rA = a2 + w * (a1 - a2);
    float rB = b2 + w * (b1 - b2);
    float v = rB + wy0 * (rA - rB);
    n.y = v * s + c0;
  }
  {
    float w = (1.0f - (dx0 + 2.0f * DXS) * csc) * SXI;
    float rA = a3 + w * (a2 - a3);
    float rB = b3 + w * (b2 - b3);
    float v = rB + wy0 * (rA - rB);
    n.z = v * s + c0;
  }
  {
    float w = (1.0f - (dx0 + 3.0f * DXS) * csc) * SXI;
    float rA = a4 + w * (a3 - a4);
    float rB = b4 + w * (b3 - b4);
    float v = rB + wy0 * (rA - rB);
    n.w = v * s + c0;
  }
  float4 cn;  // 1 - n, for fma form
  cn.x = 1.0f - n.x; cn.y = 1.0f - n.y; cn.z = 1.0f - n.z; cn.w = 1.0f - n.w;

  float4 o;
  o.x = fminf(fmaxf(A0.x * cn.x + n.x, 0.0f), 1.0f);
  o.y = fminf(fmaxf(A0.y * cn.y + n.y, 0.0f), 1.0f);
  o.z = fminf(fmaxf(A0.z * cn.z + n.z, 0.0f), 1.0f);
  o.w = fminf(fmaxf(A0.w * cn.w + n.w, 0.0f), 1.0f);
  out[base] = o;
  o.x = fminf(fmaxf(A1.x * cn.x + n.x, 0.0f), 1.0f);
  o.y = fminf(fmaxf(A1.y * cn.y + n.y, 0.0f), 1.0f);
  o.z = fminf(fmaxf(A1.z * cn.z + n.z, 0.0f), 1.0f);
  o.w = fminf(fmaxf(A1.w * cn.w + n.w, 0.0f), 1.0f);
  out[base + 65536] = o;
}

extern "C" void kernel_launch(void* const* d_in, const int* in_sizes, int n_in,
                              void* d_out, int out_size, void* d_ws, size_t ws_size,
                              hipStream_t stream) {
  const float* img = (const float*)d_in[0];
  float* out = (float*)d_out;
  unsigned char* ws = (unsigned char*)d_ws;

  unsigned* mmx = (unsigned*)ws;
  float* hm = (float*)(ws + 16);

  // diamond-square with fused exact minmax: 4 dispatches, no grid.sync
  hipLaunchKernelGGL(k_ds_small, dim3(1), dim3(1024), 0, stream, hm, mmx);
  hipLaunchKernelGGL(k_level, dim3(16), dim3(256), 0, stream, hm, mmx, 6);
  hipLaunchKernelGGL(k_level, dim3(64), dim3(256), 0, stream, hm, mmx, 7);
  hipLaunchKernelGGL(k_level, dim3(256), dim3(256), 0, stream, hm, mmx, 8);

  // fused noise + apply: 3.15M threads, each one float4 pos x 2 planes
  hipLaunchKernelGGL(k_apply_fused, dim3(32 * 3 * 512 * 512 / 4 / PPT / 256),
                     dim3(256), 0, stream,
                     (const float4*)img, hm, mmx, (float4*)out);
}